// Round 1
// baseline (540.398 us; speedup 1.0000x reference)
//
#include <hip/hip_runtime.h>

#define A_N 49104
#define B_N 16
#define C_N 90
#define KP 1024     // padded top-list length (top-1000 used)
#define MROWS 1088  // mask rows incl. prefetch pad (1024 + 16*4)

// ---------------- K1: per-anchor class max + argmax ----------------
__global__ __launch_bounds__(256) void k_score(
    const float* __restrict__ classification,
    float* __restrict__ smax, int* __restrict__ cls) {
  int a = blockIdx.x * 256 + threadIdx.x;
  int b = blockIdx.y;
  if (a >= A_N) return;
  const float2* cp2 = (const float2*)(classification + ((size_t)b * A_N + a) * C_N);
  float m = -1.0f; int am = 0;
#pragma unroll
  for (int k = 0; k < C_N / 2; ++k) {
    float2 v = cp2[k];
    if (v.x > m) { m = v.x; am = 2 * k; }
    if (v.y > m) { m = v.y; am = 2 * k + 1; }
  }
  size_t o = (size_t)b * A_N + a;
  smax[o] = m;
  cls[o] = am;
}

// ---------------- K2: per-image top-1000 (threshold bisection + bitonic), decode ----------------
__global__ __launch_bounds__(1024) void k_select(
    const float* __restrict__ smax, const int* __restrict__ cls,
    const float* __restrict__ anchors, const float* __restrict__ regression,
    float* __restrict__ topbox, float* __restrict__ topv, int* __restrict__ topcls,
    unsigned long long* __restrict__ validb) {
  __shared__ unsigned long long cand[2048];
  __shared__ unsigned s_red[16];
  __shared__ unsigned s_tot;
  __shared__ int s_cnt;
  const int tid = threadIdx.x;
  const int b = blockIdx.x;
  const int lane = tid & 63, wv = tid >> 6;
  const float* sm = smax + (size_t)b * A_N;

  // hold all 49104 score-bit values in registers (48/thread), 0 = invalid
  unsigned ub[48];
#pragma unroll
  for (int k = 0; k < 48; ++k) {
    int a = tid + k * 1024;
    float s = (a < A_N) ? sm[a] : -1.0f;
    ub[k] = (s > 0.05f) ? __float_as_uint(s) : 0u;  // positive float bits are monotonic
  }

  // bisection on bit-threshold T: largest T with count(bits >= T) >= 1000
  unsigned lo = __float_as_uint(0.05f) + 1u;
  unsigned hi = __float_as_uint(1.0f) + 1u;
  while (hi - lo > 1u) {
    unsigned mid = lo + ((hi - lo) >> 1);
    int c = 0;
#pragma unroll
    for (int k = 0; k < 48; ++k) c += (ub[k] >= mid) ? 1 : 0;
#pragma unroll
    for (int off = 32; off > 0; off >>= 1) c += __shfl_down(c, off, 64);
    if (lane == 0) s_red[wv] = (unsigned)c;
    __syncthreads();
    if (tid == 0) {
      unsigned tot = 0;
      for (int i = 0; i < 16; ++i) tot += s_red[i];
      s_tot = tot;
    }
    __syncthreads();
    if (s_tot >= 1000u) lo = mid; else hi = mid;
    __syncthreads();
  }
  const unsigned T = lo;

  // compact candidates (count in [1000, 1000+ties], ~1000 here) into LDS
  if (tid == 0) s_cnt = 0;
  __syncthreads();
#pragma unroll
  for (int k = 0; k < 48; ++k) {
    if (ub[k] >= T) {
      int a = tid + k * 1024;
      int p = atomicAdd(&s_cnt, 1);
      if (p < 2048)
        cand[p] = ~(((unsigned long long)ub[k] << 32) |
                    (unsigned long long)(0xFFFFFFFFu - (unsigned)a));
    }
  }
  __syncthreads();
  int cnt = s_cnt; if (cnt > 2048) cnt = 2048;
  for (int i = tid; i < 2048; i += 1024) if (i >= cnt) cand[i] = ~0ULL;
  __syncthreads();

  // bitonic ascending sort of inverted keys == (score desc, index asc) — matches lax.top_k
  for (int k = 2; k <= 2048; k <<= 1) {
    for (int j = k >> 1; j > 0; j >>= 1) {
      for (int i = tid; i < 2048; i += 1024) {
        int l = i ^ j;
        if (l > i) {
          unsigned long long vi = cand[i], vl = cand[l];
          if ((vi > vl) == ((i & k) == 0)) { cand[i] = vl; cand[l] = vi; }
        }
      }
      __syncthreads();
    }
  }

  // extract top-1024, decode boxes for valid entries (non-fused rounding to match numpy)
  {
    const int t = tid;
    unsigned long long key = ~cand[t];
    unsigned sb = (unsigned)(key >> 32);
    unsigned idxa = 0xFFFFFFFFu - (unsigned)(key & 0xFFFFFFFFull);
    bool v = (t < 1000) && (sb != 0u);
    float b0 = 0.f, b1 = 0.f, b2 = 0.f, b3 = 0.f, sv = -1.0f; int cl = 0;
    if (v) {
      float4 an = ((const float4*)anchors)[idxa];                       // y1,x1,y2,x2
      float4 rg = ((const float4*)regression)[(size_t)b * A_N + idxa];  // dy,dx,dh,dw
      float yca = __fmul_rn(__fadd_rn(an.x, an.z), 0.5f);
      float xca = __fmul_rn(__fadd_rn(an.y, an.w), 0.5f);
      float ha = __fsub_rn(an.z, an.x);
      float wa = __fsub_rn(an.w, an.y);
      float w  = __fmul_rn((float)exp((double)rg.w), wa);
      float h  = __fmul_rn((float)exp((double)rg.z), ha);
      float yc = __fadd_rn(__fmul_rn(rg.x, ha), yca);
      float xc = __fadd_rn(__fmul_rn(rg.y, wa), xca);
      float wh = __fmul_rn(w, 0.5f), hh = __fmul_rn(h, 0.5f);
      b0 = __fsub_rn(xc, wh); b1 = __fsub_rn(yc, hh);
      b2 = __fadd_rn(xc, wh); b3 = __fadd_rn(yc, hh);
      cl = cls[(size_t)b * A_N + idxa];
      sv = __uint_as_float(sb);
    }
    float* tb = topbox + ((size_t)b * KP + t) * 4;
    tb[0] = b0; tb[1] = b1; tb[2] = b2; tb[3] = b3;
    topv[b * KP + t] = sv;
    topcls[b * KP + t] = cl;
  }
  if (tid < 16) {
    unsigned long long vb = 0ULL;
    for (int bit = 0; bit < 64; ++bit) {
      int t = tid * 64 + bit;
      if (t < 1000 && (unsigned)((~cand[t]) >> 32) != 0u) vb |= (1ULL << bit);
    }
    validb[b * 16 + tid] = vb;
  }
}

// ---------------- K3: suppression bit-matrix (1000 rows x 16 u64 chunks) ----------------
__global__ __launch_bounds__(256) void k_mask(
    const float* __restrict__ topbox, const int* __restrict__ topcls,
    unsigned long long* __restrict__ mask) {
  __shared__ float sx1[KP], sy1[KP], sx2[KP], sy2[KP], sar[KP];
  const int b = blockIdx.y, rb = blockIdx.x;
  const int tid = threadIdx.x;
  for (int jj = tid; jj < KP; jj += 256) {
    const float* bp = topbox + ((size_t)b * KP + jj) * 4;
    float off = (float)topcls[b * KP + jj] * 4096.0f;  // class-aware NMS offset
    float x1 = __fadd_rn(bp[0], off), y1 = __fadd_rn(bp[1], off);
    float x2 = __fadd_rn(bp[2], off), y2 = __fadd_rn(bp[3], off);
    sx1[jj] = x1; sy1[jj] = y1; sx2[jj] = x2; sy2[jj] = y2;
    sar[jj] = __fmul_rn(fmaxf(__fsub_rn(x2, x1), 0.0f), fmaxf(__fsub_rn(y2, y1), 0.0f));
  }
  __syncthreads();
  const int wv = tid >> 6, lane = tid & 63;
  for (int task = wv; task < 128; task += 4) {   // 8 rows x 16 chunks
    const int r = task >> 4, cc = task & 15;
    const int i = rb * 8 + r;
    const int j = cc * 64 + lane;
    float xi1 = sx1[i], yi1 = sy1[i], xi2 = sx2[i], yi2 = sy2[i], ai = sar[i];
    float ltx = fmaxf(xi1, sx1[j]);
    float lty = fmaxf(yi1, sy1[j]);
    float rbx = fminf(xi2, sx2[j]);
    float rby = fminf(yi2, sy2[j]);
    float wx = fmaxf(__fsub_rn(rbx, ltx), 0.0f);
    float wy = fmaxf(__fsub_rn(rby, lty), 0.0f);
    float inter = __fmul_rn(wx, wy);
    float uni = fmaxf(__fsub_rn(__fadd_rn(ai, sar[j]), inter), 1e-8f);
    bool pred = (__fdiv_rn(inter, uni) > 0.5f) && (j > i) && (j < 1000);
    unsigned long long m = __ballot(pred);
    if (lane == 0) mask[((size_t)b * MROWS + i) * 16 + cc] = m;
  }
}

// ---------------- K4: sequential greedy NMS (1 wave/image) + finalize outputs ----------------
__global__ __launch_bounds__(64) void k_greedy(
    const unsigned long long* __restrict__ mask,
    const float* __restrict__ topv, const float* __restrict__ topbox,
    const int* __restrict__ topcls, const unsigned long long* __restrict__ validb,
    const float* __restrict__ scales, const float* __restrict__ pads,
    float* __restrict__ out) {
  const int b = blockIdx.x;
  const int lane = threadIdx.x;
  const int c = lane & 15, q = lane >> 4;
  const unsigned long long* M = mask + (size_t)b * MROWS * 16;
  unsigned long long remv = ~validb[b * 16 + c];  // invalid entries pre-suppressed
  unsigned long long ring[16];                    // 16-batch (64-row) prefetch ring
#pragma unroll
  for (int t = 0; t < 16; ++t) ring[t] = M[(size_t)(t * 4 + q) * 16 + c];
  __shared__ unsigned long long keepw[16];
  __shared__ int sel[100];
  __shared__ int s_cnt;
#pragma unroll 1
  for (int g = 0; g < 16; ++g) {
#pragma unroll
    for (int t = 0; t < 16; ++t) {
      const int bb = g * 16 + t;
      unsigned long long cur = ring[t];
      ring[t] = M[(size_t)((bb + 16) * 4 + q) * 16 + c];  // prefetch 16 batches ahead
#pragma unroll
      for (int q2 = 0; q2 < 4; ++q2) {
        const int i = bb * 4 + q2;
        unsigned long long w = __shfl(remv, i >> 6, 64);
        bool kept = ((w >> (i & 63)) & 1ULL) == 0ULL;
        unsigned long long srow = __shfl(cur, q2 * 16 + c, 64);
        if (kept) remv |= srow;
      }
    }
  }
  if (q == 0) keepw[c] = (~remv) & validb[b * 16 + c];
  __syncthreads();
  if (lane == 0) {
    int cnt = 0;
    for (int ci = 0; ci < 16 && cnt < 100; ++ci) {
      unsigned long long w = keepw[ci];
      while (w && cnt < 100) {
        int bit = __builtin_ctzll(w);
        sel[cnt++] = ci * 64 + bit;
        w &= (w - 1ULL);
      }
    }
    s_cnt = cnt;
  }
  __syncthreads();
  const float sy = scales[b * 2 + 0], sxx = scales[b * 2 + 1];
  const float py = pads[b * 2 + 0],  px = pads[b * 2 + 1];
  for (int s = lane; s < 100; s += 64) {
    float o0 = 0, o1 = 0, o2 = 0, o3 = 0, o4 = 0, lf = -1.0f;
    if (s < s_cnt) {
      const int i = sel[s];
      const float* bp = topbox + ((size_t)b * KP + i) * 4;
      o0 = fminf(fmaxf(__fdiv_rn(__fsub_rn(bp[0], px), sxx), 0.0f), 512.0f);
      o1 = fminf(fmaxf(__fdiv_rn(__fsub_rn(bp[1], py), sy ), 0.0f), 512.0f);
      o2 = fminf(fmaxf(__fdiv_rn(__fsub_rn(bp[2], px), sxx), 0.0f), 512.0f);
      o3 = fminf(fmaxf(__fdiv_rn(__fsub_rn(bp[3], py), sy ), 0.0f), 512.0f);
      o4 = topv[b * KP + i];
      lf = (float)topcls[b * KP + i];
    }
    float* op = out + ((size_t)b * 100 + s) * 5;
    op[0] = o0; op[1] = o1; op[2] = o2; op[3] = o3; op[4] = o4;
    out[(size_t)B_N * 500 + b * 100 + s] = lf;  // labels as float32
  }
}

extern "C" void kernel_launch(void* const* d_in, const int* in_sizes, int n_in,
                              void* d_out, int out_size, void* d_ws, size_t ws_size,
                              hipStream_t stream) {
  const float* anchors        = (const float*)d_in[0];
  const float* regression     = (const float*)d_in[1];
  const float* classification = (const float*)d_in[2];
  const float* scales         = (const float*)d_in[3];
  const float* pads           = (const float*)d_in[4];
  char* ws = (char*)d_ws;
  float* smax   = (float*)(ws + 0);          // 16*49104 f32            = 3,142,656 B
  int*   cls    = (int*)  (ws + 3142656);    // 16*49104 i32            = 3,142,656 B
  float* topbox = (float*)(ws + 6285312);    // 16*1024*4 f32           =   262,144 B
  float* topv   = (float*)(ws + 6547456);    // 16*1024 f32             =    65,536 B
  int*   topcls = (int*)  (ws + 6612992);    // 16*1024 i32             =    65,536 B
  unsigned long long* validb = (unsigned long long*)(ws + 6678528);  // 16*16 u64 = 2,048 B
  unsigned long long* mask   = (unsigned long long*)(ws + 6680576);  // 16*1088*16 u64 = 2,228,224 B
  float* out = (float*)d_out;

  k_score <<<dim3((A_N + 255) / 256, B_N), 256, 0, stream>>>(classification, smax, cls);
  k_select<<<B_N, 1024, 0, stream>>>(smax, cls, anchors, regression, topbox, topv, topcls, validb);
  k_mask  <<<dim3(125, B_N), 256, 0, stream>>>(topbox, topcls, mask);
  k_greedy<<<B_N, 64, 0, stream>>>(mask, topv, topbox, topcls, validb, scales, pads, out);
}

// Round 4
// 511.143 us; speedup vs baseline: 1.0572x; 1.0572x over previous
//
#include <hip/hip_runtime.h>

#define A_N 49104
#define B_N 16
#define C_N 90
#define KP 1024     // padded top-list length (top-1000 used)
#define MROWS 1088  // mask rows incl. prefetch pad (1024 + 16*4)
#define ANCH 128    // anchors staged per k_score block

// ---------------- K1: per-anchor class max + argmax (LDS-staged, coalesced) ----------------
__global__ __launch_bounds__(256) void k_score(
    const float* __restrict__ classification,
    float* __restrict__ smax, int* __restrict__ cls) {
  __shared__ float sc[ANCH * C_N];  // 45 KB -> 3 blocks/CU
  const int blk = blockIdx.x, b = blockIdx.y;
  const int base = blk * ANCH;
  const int nA = min(ANCH, A_N - base);
  const int nf4 = (nA * C_N) >> 2;  // nA always even -> divisible by 4
  const float4* s4 = (const float4*)(classification + ((size_t)b * A_N + base) * C_N);
  float4* d4 = (float4*)sc;
  for (int i = threadIdx.x; i < nf4; i += 256) d4[i] = s4[i];  // fully coalesced
  __syncthreads();
  const int al = threadIdx.x >> 1;     // local anchor
  const int half = threadIdx.x & 1;    // class half: 0 -> 0..44, 1 -> 45..89
  if (al < nA) {
    const float* p = sc + al * C_N + half * 45;  // word idx = 45*tid + k: stride 45, 2-way banks = free
    float m = -1.0f; int am = 0;
#pragma unroll
    for (int k = 0; k < 45; ++k) { float v = p[k]; if (v > m) { m = v; am = k; } }
    float m2 = __shfl_xor(m, 1, 64);
    int am2 = __shfl_xor(am, 1, 64);
    if (half == 0) {
      float mm = m; int aa = am;
      if (m2 > mm) { mm = m2; aa = 45 + am2; }  // strict >: ties keep lower class (argmax semantics)
      size_t o = (size_t)b * A_N + base + al;
      smax[o] = mm; cls[o] = aa;
    }
  }
}

// ---------------- K2: per-image top-1000 (histogram radix-select + bitonic), decode ----------------
__global__ __launch_bounds__(1024) void k_select(
    const float* __restrict__ smax, const int* __restrict__ cls,
    const float* __restrict__ anchors, const float* __restrict__ regression,
    float* __restrict__ topbox, float* __restrict__ topv, int* __restrict__ topcls,
    unsigned long long* __restrict__ validb) {
  __shared__ unsigned long long cand[2048];
  __shared__ unsigned hist[4096];
  __shared__ unsigned s_T, s_cntT, s_binCnt, s_done;
  __shared__ int s_cnt;
  const int tid = threadIdx.x;
  const int b = blockIdx.x;
  const int lane = tid & 63, wv = tid >> 6;
  const float* sm = smax + (size_t)b * A_N;

  // hold all 49104 score-bit values in registers (48/thread), 0 = invalid
  unsigned ub[48];
#pragma unroll
  for (int k = 0; k < 48; ++k) {
    int a = tid + k * 1024;
    float s = (a < A_N) ? sm[a] : -1.0f;
    ub[k] = (s > 0.05f) ? __float_as_uint(s) : 0u;  // positive float bits are monotonic
  }

  // histogram radix-select: largest T with count(bits >= T) >= 1000, count <= 2048 (refine if heavy bin)
  unsigned lo = 0x3D4CCCCEu;                 // smallest bits with s > 0.05f
  unsigned width = 0x3F800001u - lo;         // covers up through 1.0f
  unsigned baseCnt = 0, T = lo;
  for (int pass = 0; pass < 4; ++pass) {
    int sh = 0;
    while ((((width - 1u) >> sh) + 1u) > 4096u) ++sh;
    const unsigned nb = ((width - 1u) >> sh) + 1u;
    for (int i = tid; i < 4096; i += 1024) hist[i] = 0u;
    __syncthreads();
#pragma unroll
    for (int k = 0; k < 48; ++k) {
      unsigned u = ub[k];
      if (u >= lo && (u - lo) < width) atomicAdd(&hist[(u - lo) >> sh], 1u);
    }
    __syncthreads();
    if (wv == 0) {
      unsigned run = baseCnt; int B = -1; unsigned cnt = 0, binc = 0;
      for (int start = (int)nb - 64; B < 0; start -= 64) {
        int idx = start + lane;
        unsigned v = (idx >= 0 && idx < (int)nb) ? hist[idx] : 0u;
        unsigned sfx = v;  // suffix sum within chunk: sum over lanes >= lane
        for (int off = 1; off < 64; off <<= 1) {
          unsigned o = __shfl_down(sfx, off, 64);
          if (lane + off < 64) sfx += o;
        }
        unsigned chunkTot = __shfl(sfx, 0, 64);
        if (run + chunkTot >= 1000u) {
          bool cond = (idx >= 0) && (run + sfx >= 1000u);
          unsigned long long bal = __ballot(cond);
          int top = 63 - __clzll(bal);
          B = start + top;
          cnt = run + __shfl(sfx, top, 64);
          binc = __shfl(v, top, 64);
        } else {
          run += chunkTot;
        }
        if (start <= -63 && B < 0) { B = 0; cnt = run; binc = 0; }  // < 1000 valid total
      }
      if (lane == 0) {
        s_T = lo + ((unsigned)B << sh);
        s_cntT = cnt; s_binCnt = binc;
        s_done = (cnt <= 2048u || sh == 0) ? 1u : 0u;
      }
    }
    __syncthreads();
    T = s_T;
    if (s_done) break;
    baseCnt = s_cntT - s_binCnt;  // count >= upper edge of chosen bin
    int sh2 = 0;
    while ((((width - 1u) >> sh2) + 1u) > 4096u) ++sh2;
    lo = s_T; width = 1u << sh2;
    __syncthreads();
  }

  // compact candidates into LDS
  if (tid == 0) s_cnt = 0;
  __syncthreads();
#pragma unroll
  for (int k = 0; k < 48; ++k) {
    if (ub[k] >= T) {
      int a = tid + k * 1024;
      int p = atomicAdd(&s_cnt, 1);
      if (p < 2048)
        cand[p] = ~(((unsigned long long)ub[k] << 32) |
                    (unsigned long long)(0xFFFFFFFFu - (unsigned)a));
    }
  }
  __syncthreads();
  int cnt = s_cnt; if (cnt > 2048) cnt = 2048;
  for (int i = tid; i < 2048; i += 1024) if (i >= cnt) cand[i] = ~0ULL;
  __syncthreads();

  // bitonic ascending sort of inverted keys == (score desc, index asc) — matches lax.top_k
  for (int k = 2; k <= 2048; k <<= 1) {
    for (int j = k >> 1; j > 0; j >>= 1) {
      for (int i = tid; i < 2048; i += 1024) {
        int l = i ^ j;
        if (l > i) {
          unsigned long long vi = cand[i], vl = cand[l];
          if ((vi > vl) == ((i & k) == 0)) { cand[i] = vl; cand[l] = vi; }
        }
      }
      __syncthreads();
    }
  }

  // extract top-1024, decode boxes for valid entries (non-fused rounding to match numpy)
  {
    const int t = tid;
    unsigned long long key = ~cand[t];
    unsigned sb = (unsigned)(key >> 32);
    unsigned idxa = 0xFFFFFFFFu - (unsigned)(key & 0xFFFFFFFFull);
    bool v = (t < 1000) && (sb != 0u);
    float b0 = 0.f, b1 = 0.f, b2 = 0.f, b3 = 0.f, sv = -1.0f; int cl = 0;
    if (v) {
      float4 an = ((const float4*)anchors)[idxa];                       // y1,x1,y2,x2
      float4 rg = ((const float4*)regression)[(size_t)b * A_N + idxa];  // dy,dx,dh,dw
      float yca = __fmul_rn(__fadd_rn(an.x, an.z), 0.5f);
      float xca = __fmul_rn(__fadd_rn(an.y, an.w), 0.5f);
      float ha = __fsub_rn(an.z, an.x);
      float wa = __fsub_rn(an.w, an.y);
      float w  = __fmul_rn((float)exp((double)rg.w), wa);
      float h  = __fmul_rn((float)exp((double)rg.z), ha);
      float yc = __fadd_rn(__fmul_rn(rg.x, ha), yca);
      float xc = __fadd_rn(__fmul_rn(rg.y, wa), xca);
      float wh = __fmul_rn(w, 0.5f), hh = __fmul_rn(h, 0.5f);
      b0 = __fsub_rn(xc, wh); b1 = __fsub_rn(yc, hh);
      b2 = __fadd_rn(xc, wh); b3 = __fadd_rn(yc, hh);
      cl = cls[(size_t)b * A_N + idxa];
      sv = __uint_as_float(sb);
    }
    float* tb = topbox + ((size_t)b * KP + t) * 4;
    tb[0] = b0; tb[1] = b1; tb[2] = b2; tb[3] = b3;
    topv[b * KP + t] = sv;
    topcls[b * KP + t] = cl;
  }
  if (tid < 16) {
    unsigned long long vb = 0ULL;
    for (int bit = 0; bit < 64; ++bit) {
      int t = tid * 64 + bit;
      if (t < 1000 && (unsigned)((~cand[t]) >> 32) != 0u) vb |= (1ULL << bit);
    }
    validb[b * 16 + tid] = vb;
  }
}

// ---------------- K3: suppression bit-matrix (1000 rows x 16 u64 chunks) ----------------
__global__ __launch_bounds__(256) void k_mask(
    const float* __restrict__ topbox, const int* __restrict__ topcls,
    unsigned long long* __restrict__ mask) {
  __shared__ float sx1[KP], sy1[KP], sx2[KP], sy2[KP], sar[KP];
  const int b = blockIdx.y, rb = blockIdx.x;
  const int tid = threadIdx.x;
  for (int jj = tid; jj < KP; jj += 256) {
    const float* bp = topbox + ((size_t)b * KP + jj) * 4;
    float off = (float)topcls[b * KP + jj] * 4096.0f;  // class-aware NMS offset
    float x1 = __fadd_rn(bp[0], off), y1 = __fadd_rn(bp[1], off);
    float x2 = __fadd_rn(bp[2], off), y2 = __fadd_rn(bp[3], off);
    sx1[jj] = x1; sy1[jj] = y1; sx2[jj] = x2; sy2[jj] = y2;
    sar[jj] = __fmul_rn(fmaxf(__fsub_rn(x2, x1), 0.0f), fmaxf(__fsub_rn(y2, y1), 0.0f));
  }
  __syncthreads();
  const int wv = tid >> 6, lane = tid & 63;
  for (int task = wv; task < 128; task += 4) {   // 8 rows x 16 chunks
    const int r = task >> 4, cc = task & 15;
    const int i = rb * 8 + r;
    const int j = cc * 64 + lane;
    float xi1 = sx1[i], yi1 = sy1[i], xi2 = sx2[i], yi2 = sy2[i], ai = sar[i];
    float ltx = fmaxf(xi1, sx1[j]);
    float lty = fmaxf(yi1, sy1[j]);
    float rbx = fminf(xi2, sx2[j]);
    float rby = fminf(yi2, sy2[j]);
    float wx = fmaxf(__fsub_rn(rbx, ltx), 0.0f);
    float wy = fmaxf(__fsub_rn(rby, lty), 0.0f);
    float inter = __fmul_rn(wx, wy);
    float uni = fmaxf(__fsub_rn(__fadd_rn(ai, sar[j]), inter), 1e-8f);
    bool pred = (__fdiv_rn(inter, uni) > 0.5f) && (j > i) && (j < 1000);
    unsigned long long m = __ballot(pred);
    if (lane == 0) mask[((size_t)b * MROWS + i) * 16 + cc] = m;
  }
}

// ---------------- K4: sequential greedy NMS (1 wave/image) + finalize outputs ----------------
__global__ __launch_bounds__(64) void k_greedy(
    const unsigned long long* __restrict__ mask,
    const float* __restrict__ topv, const float* __restrict__ topbox,
    const int* __restrict__ topcls, const unsigned long long* __restrict__ validb,
    const float* __restrict__ scales, const float* __restrict__ pads,
    float* __restrict__ out) {
  const int b = blockIdx.x;
  const int lane = threadIdx.x;
  const int c = lane & 15, q = lane >> 4;
  const unsigned long long* M = mask + (size_t)b * MROWS * 16;
  unsigned long long remv = ~validb[b * 16 + c];  // invalid entries pre-suppressed
  unsigned long long ring[16];                    // 16-batch (64-row) prefetch ring
#pragma unroll
  for (int t = 0; t < 16; ++t) ring[t] = M[(size_t)(t * 4 + q) * 16 + c];
  __shared__ unsigned long long keepw[16];
  __shared__ int sel[100];
  __shared__ int s_cnt;
#pragma unroll 1
  for (int g = 0; g < 16; ++g) {
#pragma unroll
    for (int t = 0; t < 16; ++t) {
      const int bb = g * 16 + t;
      unsigned long long cur = ring[t];
      ring[t] = M[(size_t)((bb + 16) * 4 + q) * 16 + c];  // prefetch 16 batches ahead
#pragma unroll
      for (int q2 = 0; q2 < 4; ++q2) {
        const int i = bb * 4 + q2;
        unsigned long long w = __shfl(remv, i >> 6, 64);
        bool kept = ((w >> (i & 63)) & 1ULL) == 0ULL;
        unsigned long long srow = __shfl(cur, q2 * 16 + c, 64);
        if (kept) remv |= srow;
      }
    }
  }
  if (q == 0) keepw[c] = (~remv) & validb[b * 16 + c];
  __syncthreads();
  if (lane == 0) {
    int cnt = 0;
    for (int ci = 0; ci < 16 && cnt < 100; ++ci) {
      unsigned long long w = keepw[ci];
      while (w && cnt < 100) {
        int bit = __builtin_ctzll(w);
        sel[cnt++] = ci * 64 + bit;
        w &= (w - 1ULL);
      }
    }
    s_cnt = cnt;
  }
  __syncthreads();
  const float sy = scales[b * 2 + 0], sxx = scales[b * 2 + 1];
  const float py = pads[b * 2 + 0],  px = pads[b * 2 + 1];
  for (int s = lane; s < 100; s += 64) {
    float o0 = 0, o1 = 0, o2 = 0, o3 = 0, o4 = 0, lf = -1.0f;
    if (s < s_cnt) {
      const int i = sel[s];
      const float* bp = topbox + ((size_t)b * KP + i) * 4;
      o0 = fminf(fmaxf(__fdiv_rn(__fsub_rn(bp[0], px), sxx), 0.0f), 512.0f);
      o1 = fminf(fmaxf(__fdiv_rn(__fsub_rn(bp[1], py), sy ), 0.0f), 512.0f);
      o2 = fminf(fmaxf(__fdiv_rn(__fsub_rn(bp[2], px), sxx), 0.0f), 512.0f);
      o3 = fminf(fmaxf(__fdiv_rn(__fsub_rn(bp[3], py), sy ), 0.0f), 512.0f);
      o4 = topv[b * KP + i];
      lf = (float)topcls[b * KP + i];
    }
    float* op = out + ((size_t)b * 100 + s) * 5;
    op[0] = o0; op[1] = o1; op[2] = o2; op[3] = o3; op[4] = o4;
    out[(size_t)B_N * 500 + b * 100 + s] = lf;  // labels as float32
  }
}

extern "C" void kernel_launch(void* const* d_in, const int* in_sizes, int n_in,
                              void* d_out, int out_size, void* d_ws, size_t ws_size,
                              hipStream_t stream) {
  const float* anchors        = (const float*)d_in[0];
  const float* regression     = (const float*)d_in[1];
  const float* classification = (const float*)d_in[2];
  const float* scales         = (const float*)d_in[3];
  const float* pads           = (const float*)d_in[4];
  char* ws = (char*)d_ws;
  float* smax   = (float*)(ws + 0);          // 16*49104 f32            = 3,142,656 B
  int*   cls    = (int*)  (ws + 3142656);    // 16*49104 i32            = 3,142,656 B
  float* topbox = (float*)(ws + 6285312);    // 16*1024*4 f32           =   262,144 B
  float* topv   = (float*)(ws + 6547456);    // 16*1024 f32             =    65,536 B
  int*   topcls = (int*)  (ws + 6612992);    // 16*1024 i32             =    65,536 B
  unsigned long long* validb = (unsigned long long*)(ws + 6678528);  // 16*16 u64 = 2,048 B
  unsigned long long* mask   = (unsigned long long*)(ws + 6680576);  // 16*1088*16 u64 = 2,228,224 B
  float* out = (float*)d_out;

  k_score <<<dim3((A_N + ANCH - 1) / ANCH, B_N), 256, 0, stream>>>(classification, smax, cls);
  k_select<<<B_N, 1024, 0, stream>>>(smax, cls, anchors, regression, topbox, topv, topcls, validb);
  k_mask  <<<dim3(125, B_N), 256, 0, stream>>>(topbox, topcls, mask);
  k_greedy<<<B_N, 64, 0, stream>>>(mask, topv, topbox, topcls, validb, scales, pads, out);
}